// Round 12
// baseline (26.179 us; speedup 1.0000x reference)
//
#include <hip/hip_runtime.h>
#include <math.h>

// SphericalBessel, rev-space closed form + clamp tail, store-smeared pipeline.
// Theory: 24.5us plateau = store duty-cycle loss (bursty per-tile flushes, blocks
// phase-locked -> HBM write pipe idles ~40%). Fix: double-buffered LDS, flush of
// tile t-1 interleaved into compute of tile t at mode granularity (sched_barrier
// pins each store's issue point), raw s_barrier without vmcnt drain.

static constexpr int KMODES = 100;
static constexpr int NTILE  = 64;
static constexpr int TPB    = 4;                   // tiles per block
static constexpr int TILE_ELEMS = NTILE * KMODES;  // 6400
static constexpr double PI_D   = 3.14159265358979323846;
static constexpr double BETA_D = 1.0 / (2.0 * PI_D);
static constexpr double S2PI_D = 0.79788456080286535588;

__device__ __forceinline__ float rcpf(float x) { return __builtin_amdgcn_rcpf(x); }
__device__ __forceinline__ float sin_rev(float a) { float r; asm("v_sin_f32 %0, %1" : "=v"(r) : "v"(a)); return r; }
__device__ __forceinline__ float cos_rev(float a) { float r; asm("v_cos_f32 %0, %1" : "=v"(r) : "v"(a)); return r; }

// raw integer closed-form z-polys (z = 1/x^2), highest degree first (R4-verified)
template<int L> struct ZC;
template<> struct ZC<2>{ static constexpr double sg[2]={3,-1};                              static constexpr double gm[1]={-3}; };
template<> struct ZC<3>{ static constexpr double sg[2]={15,-6};                             static constexpr double gm[2]={-15,1}; };
template<> struct ZC<4>{ static constexpr double sg[3]={105,-45,1};                         static constexpr double gm[2]={-105,10}; };
template<> struct ZC<5>{ static constexpr double sg[3]={945,-420,15};                       static constexpr double gm[3]={-945,105,-1}; };
template<> struct ZC<6>{ static constexpr double sg[4]={10395,-4725,210,-1};                static constexpr double gm[3]={-10395,1260,-21}; };
template<> struct ZC<7>{ static constexpr double sg[4]={135135,-62370,3150,-28};            static constexpr double gm[4]={-135135,17325,-378,1}; };
template<> struct ZC<8>{ static constexpr double sg[5]={2027025,-945945,51975,-630,1};      static constexpr double gm[4]={-2027025,270270,-6930,36}; };
template<> struct ZC<9>{ static constexpr double sg[5]={34459425,-16216200,945945,-13860,45}; static constexpr double gm[5]={-34459425,4729725,-135135,990,-1}; };

// w-space scaled coefficients (R10-validated): out = (kv*w) * inner, w = rcp(arg),
// arg = x/(2pi);  odd L: inner = s*w*SG(y) + c*GM(y);  even L: inner = c*w*GM(y) + s*SG(y)
template<int L> struct WC {
  static constexpr int NS = L / 2 + 1, NG = (L + 1) / 2;
  float sg[NS], gm[NG], xc;
  constexpr WC() : sg{}, gm{}, xc(0.f) {
    constexpr double XT[10] = {0,0,0.088,0.29,0.61,1.01,1.48,2.00,2.55,3.14};
    for (int i = 0; i < NS; ++i) {
      int deg = NS - 1 - i, e = (L & 1) ? (2*deg + 2) : (2*deg + 1);
      double s = S2PI_D; for (int t = 0; t < e; ++t) s *= BETA_D;
      sg[i] = (float)(s * ZC<L>::sg[i]);
    }
    for (int i = 0; i < NG; ++i) {
      int deg = NG - 1 - i, e = (L & 1) ? (2*deg + 1) : (2*deg + 2);
      double s = S2PI_D; for (int t = 0; t < e; ++t) s *= BETA_D;
      gm[i] = (float)(s * ZC<L>::gm[i]);
    }
    xc = (float)(XT[L] * BETA_D);
  }
};

template<int N>
__device__ __forceinline__ float polyH(float y, const float (&a)[N]) {
  float h = a[0];
#pragma unroll
  for (int i = 1; i < N; ++i) h = fmaf(h, y, a[i]);
  return h;
}

// interleaved flusher: 7 float4 LDS->global steps per thread per tile
struct Flusher {
  const float* src; float* dst; int it; int tid;
  __device__ __forceinline__ void step() {
    if (src != nullptr && it < 7) {
      int e = it * 1024 + tid * 4;
      if (it < 6 || tid < 64) {           // tail: 6400 = 6*1024 + 256
        float4 v = *reinterpret_cast<const float4*>(src + e);
        *reinterpret_cast<float4*>(dst + e) = v;
      }
      ++it;
      __builtin_amdgcn_sched_barrier(0);  // pin store issue point (don't re-cluster)
    }
  }
  __device__ __forceinline__ void finish() {
    if (src != nullptr) { while (it < 7) step(); }
  }
};

template<int L>
__device__ __forceinline__ void do_l(float rvb, const float* __restrict__ kvec,
                                     float* ldsrow, Flusher& fl) {
#pragma unroll
  for (int m = 0; m < 2 * L + 1; ++m) {
    const int KK = L * L + m;
    float kv = kvec[KK];                 // uniform -> s_load
    float arg = rvb * kv;                // x in revolutions
    float res;
    if constexpr (L == 0) {
      float w = rcpf(arg);
      res = (sin_rev(arg) * (float)(S2PI_D * BETA_D)) * (kv * w);
    } else if constexpr (L == 1) {
      float w = rcpf(arg);
      float s = sin_rev(arg), c = cos_rev(arg);
      float inner = fmaf(s * w, (float)(S2PI_D * BETA_D * BETA_D),
                         -(c * (float)(S2PI_D * BETA_D)));
      res = (kv * w) * inner;
    } else {
      constexpr WC<L> wc{};              // scoped here: WC<0>/WC<1> never instantiated
      float argc = fmaxf(arg, wc.xc);    // clamp tail: j_l(xcut), |err|<=4e-3
      float w = rcpf(argc);
      float s = sin_rev(argc), c = cos_rev(argc);
      float y = w * w;
      float sgv = polyH(y, wc.sg);
      float gmv = polyH(y, wc.gm);
      float inner;
      if constexpr (L & 1) inner = fmaf(s * w, sgv, c * gmv);
      else                 inner = fmaf(c * w, gmv, s * sgv);
      res = (kv * w) * inner;
    }
    ldsrow[KK] = res;
    if ((m % 3) == 2) fl.step();         // smear prev-tile stores through compute
  }
}

__global__ __launch_bounds__(256) void sbf_kernel(const float* __restrict__ r,
                                                  const float* __restrict__ kvec,
                                                  float* __restrict__ out) {
  __shared__ float buf[2][TILE_ELEMS];     // 51.2 KB -> 3 blocks/CU
  const int tid = threadIdx.x;
  const int w = tid >> 6, lane = tid & 63;
  const int tile0 = blockIdx.x * TPB;

  float rvb[TPB];
#pragma unroll
  for (int t = 0; t < TPB; ++t)
    rvb[t] = r[(tile0 + t) * NTILE + lane] * (float)BETA_D;

  Flusher fl{nullptr, nullptr, 7, tid};
#pragma unroll
  for (int t = 0; t < TPB; ++t) {
    float* ldsrow = &buf[t & 1][lane * KMODES];
    // compute tile t (writes buf[t&1]) while flushing tile t-1 (reads buf[(t&1)^1])
    if (w == 0)      { do_l<9>(rvb[t], kvec, ldsrow, fl); do_l<2>(rvb[t], kvec, ldsrow, fl); }
    else if (w == 1) { do_l<8>(rvb[t], kvec, ldsrow, fl); do_l<3>(rvb[t], kvec, ldsrow, fl); }
    else if (w == 2) { do_l<7>(rvb[t], kvec, ldsrow, fl); do_l<4>(rvb[t], kvec, ldsrow, fl); do_l<0>(rvb[t], kvec, ldsrow, fl); }
    else             { do_l<6>(rvb[t], kvec, ldsrow, fl); do_l<5>(rvb[t], kvec, ldsrow, fl); do_l<1>(rvb[t], kvec, ldsrow, fl); }
    fl.finish();                           // any remaining prev-tile stores
    // LDS ops retired (ds_writes of t visible, flush reads of t-1 done);
    // global stores stay in flight -- NO vmcnt drain in the main loop.
    asm volatile("s_waitcnt lgkmcnt(0)" ::: "memory");
    __builtin_amdgcn_s_barrier();
    fl.src = &buf[t & 1][0];
    fl.dst = out + (size_t)(tile0 + t) * TILE_ELEMS;
    fl.it = 0;
  }
  fl.finish();                             // epilogue: flush last tile
}

extern "C" void kernel_launch(void* const* d_in, const int* in_sizes, int n_in,
                              void* d_out, int out_size, void* d_ws, size_t ws_size,
                              hipStream_t stream) {
  const float* r = (const float*)d_in[0];
  const float* k = (const float*)d_in[1];
  float* out = (float*)d_out;
  int N = in_sizes[0];                   // 262144
  int blocks = N / NTILE / TPB;          // 1024
  sbf_kernel<<<blocks, 256, 0, stream>>>(r, k, out);
}

// Round 13
// 25.731 us; speedup vs baseline: 1.0174x; 1.0174x over previous
//
#include <hip/hip_runtime.h>
#include <math.h>

// SphericalBessel, rev-space closed form + clamp tail — LOOPED (small-code) variant.
// Theory under test: the 24.5us plateau is instruction-FETCH bound (20KB unrolled
// hot code x 4 divergent wave paths thrashes I-cache; explains insensitivity to
// scheduling/LDS/store changes). Per-mode bodies are now runtime loops (~30 inst),
// coefficients still compile-time per l. Everything else = validated R9 structure.

static constexpr int KMODES  = 100;
static constexpr int NTILE   = 64;
static constexpr int LSTRIDE = 102;   // even: 8B-aligned flush quads; writes 4-way (ok)
static constexpr double PI_D   = 3.14159265358979323846;
static constexpr double BETA_D = 1.0 / (2.0 * PI_D);
static constexpr double S2PI_D = 0.79788456080286535588;

__device__ __forceinline__ float rcpf(float x) { return __builtin_amdgcn_rcpf(x); }
__device__ __forceinline__ float sin_rev(float a) { float r; asm("v_sin_f32 %0, %1" : "=v"(r) : "v"(a)); return r; }
__device__ __forceinline__ float cos_rev(float a) { float r; asm("v_cos_f32 %0, %1" : "=v"(r) : "v"(a)); return r; }

// raw integer closed-form z-polys (z = 1/x^2), highest degree first (R4-verified)
template<int L> struct ZC;
template<> struct ZC<2>{ static constexpr double sg[2]={3,-1};                              static constexpr double gm[1]={-3}; };
template<> struct ZC<3>{ static constexpr double sg[2]={15,-6};                             static constexpr double gm[2]={-15,1}; };
template<> struct ZC<4>{ static constexpr double sg[3]={105,-45,1};                         static constexpr double gm[2]={-105,10}; };
template<> struct ZC<5>{ static constexpr double sg[3]={945,-420,15};                       static constexpr double gm[3]={-945,105,-1}; };
template<> struct ZC<6>{ static constexpr double sg[4]={10395,-4725,210,-1};                static constexpr double gm[3]={-10395,1260,-21}; };
template<> struct ZC<7>{ static constexpr double sg[4]={135135,-62370,3150,-28};            static constexpr double gm[4]={-135135,17325,-378,1}; };
template<> struct ZC<8>{ static constexpr double sg[5]={2027025,-945945,51975,-630,1};      static constexpr double gm[4]={-2027025,270270,-6930,36}; };
template<> struct ZC<9>{ static constexpr double sg[5]={34459425,-16216200,945945,-13860,45}; static constexpr double gm[5]={-34459425,4729725,-135135,990,-1}; };

// w-space scaled coefficients (R10-validated): out = (kv*w) * inner, w = rcp(arg),
// arg = x/(2pi);  odd L: inner = s*w*SG(y) + c*GM(y);  even L: inner = c*w*GM(y) + s*SG(y)
template<int L> struct WC {
  static constexpr int NS = L / 2 + 1, NG = (L + 1) / 2;
  float sg[NS], gm[NG], xc;
  constexpr WC() : sg{}, gm{}, xc(0.f) {
    constexpr double XT[10] = {0,0,0.088,0.29,0.61,1.01,1.48,2.00,2.55,3.14};
    for (int i = 0; i < NS; ++i) {
      int deg = NS - 1 - i, e = (L & 1) ? (2*deg + 2) : (2*deg + 1);
      double s = S2PI_D; for (int t = 0; t < e; ++t) s *= BETA_D;
      sg[i] = (float)(s * ZC<L>::sg[i]);
    }
    for (int i = 0; i < NG; ++i) {
      int deg = NG - 1 - i, e = (L & 1) ? (2*deg + 1) : (2*deg + 2);
      double s = S2PI_D; for (int t = 0; t < e; ++t) s *= BETA_D;
      gm[i] = (float)(s * ZC<L>::gm[i]);
    }
    xc = (float)(XT[L] * BETA_D);
  }
};

template<int N>
__device__ __forceinline__ float polyH(float y, const float (&a)[N]) {
  float h = a[0];
#pragma unroll
  for (int i = 1; i < N; ++i) h = fmaf(h, y, a[i]);
  return h;
}

template<int L>
__device__ __forceinline__ void do_l(float rv, const float2* __restrict__ ktab,
                                     float* ldsrow) {
  const float2* kp = ktab + L * L;
  float* dst = ldsrow + L * L;
  if constexpr (L == 0) {
    float2 k2 = kp[0];
    float arg = rv * k2.x;
    float w = rcpf(arg);
    dst[0] = (sin_rev(arg) * (float)(S2PI_D * BETA_D)) * (k2.y * w);
  } else if constexpr (L == 1) {
#pragma unroll 1
    for (int m = 0; m < 3; ++m) {
      float2 k2 = kp[m];
      float arg = rv * k2.x;
      float w = rcpf(arg);
      float s = sin_rev(arg), c = cos_rev(arg);
      float inner = fmaf(s * w, (float)(S2PI_D * BETA_D * BETA_D),
                         -(c * (float)(S2PI_D * BETA_D)));
      dst[m] = (k2.y * w) * inner;
    }
  } else {
    constexpr WC<L> wc{};                // only instantiated for L>=2
#pragma unroll 1
    for (int m = 0; m < 2 * L + 1; ++m) {
      float2 k2 = kp[m];                 // broadcast ds_read_b64
      float arg = rv * k2.x;             // x in revolutions
      float argc = fmaxf(arg, wc.xc);    // clamp tail: j_l(xcut), |err|<=4e-3
      float w = rcpf(argc);
      float s = sin_rev(argc), c = cos_rev(argc);
      float y = w * w;
      float sgv = polyH(y, wc.sg);       // Horner unrolled (compile-time L)
      float gmv = polyH(y, wc.gm);
      float inner;
      if constexpr (L & 1) inner = fmaf(s * w, sgv, c * gmv);
      else                 inner = fmaf(c * w, gmv, s * sgv);
      dst[m] = (k2.y * w) * inner;
    }
  }
}

__global__ __launch_bounds__(256) void sbf_kernel(const float* __restrict__ r,
                                                  const float* __restrict__ kvec,
                                                  float* __restrict__ out) {
  __shared__ float2 ktab[KMODES];          // 800 B
  __shared__ float lds[NTILE * LSTRIDE];   // 26.1 KB -> 6 blocks/CU
  const int tid = threadIdx.x;
  const int w = tid >> 6, lane = tid & 63;
  const int n0 = blockIdx.x * NTILE;
  if (tid < KMODES) {
    float kv = kvec[tid];
    ktab[tid] = make_float2(kv * (float)BETA_D, kv);
  }
  float rv = r[n0 + lane];
  float* ldsrow = &lds[lane * LSTRIDE];
  __syncthreads();                          // ktab ready
  // cost-balanced l-partition (uniform-cost model: 536/510/485/499)
  if (w == 0)      { do_l<9>(rv, ktab, ldsrow); do_l<2>(rv, ktab, ldsrow); }
  else if (w == 1) { do_l<8>(rv, ktab, ldsrow); do_l<3>(rv, ktab, ldsrow); }
  else if (w == 2) { do_l<7>(rv, ktab, ldsrow); do_l<4>(rv, ktab, ldsrow); do_l<0>(rv, ktab, ldsrow); }
  else             { do_l<6>(rv, ktab, ldsrow); do_l<5>(rv, ktab, ldsrow); do_l<1>(rv, ktab, ldsrow); }
  __syncthreads();
  // flush (R9-verified): contiguous float4 global stores; LDS float2-pair gather,
  // padded-row word index tracked incrementally (e += 1024 -> +10 rows, +24 cols)
  unsigned e0 = (unsigned)tid * 4u;
  int row = (int)(e0 / 100u);
  int col = (int)e0 - row * 100;
  int wi  = row * LSTRIDE + col;
  float* gout = out + (size_t)n0 * KMODES + e0;
#pragma unroll
  for (int it = 0; it < 6; ++it) {
    float2 lo = *reinterpret_cast<const float2*>(&lds[wi]);
    float2 hi = *reinterpret_cast<const float2*>(&lds[wi + 2]);
    *reinterpret_cast<float4*>(gout + it * 1024) = make_float4(lo.x, lo.y, hi.x, hi.y);
    col += 24; wi += 1044;
    if (col >= 100) { col -= 100; wi += 2; }
  }
  if (tid < 64) {
    float2 lo = *reinterpret_cast<const float2*>(&lds[wi]);
    float2 hi = *reinterpret_cast<const float2*>(&lds[wi + 2]);
    *reinterpret_cast<float4*>(gout + 6 * 1024) = make_float4(lo.x, lo.y, hi.x, hi.y);
  }
}

extern "C" void kernel_launch(void* const* d_in, const int* in_sizes, int n_in,
                              void* d_out, int out_size, void* d_ws, size_t ws_size,
                              hipStream_t stream) {
  const float* r = (const float*)d_in[0];
  const float* k = (const float*)d_in[1];
  float* out = (float*)d_out;
  int N = in_sizes[0];                   // 262144
  int blocks = N / NTILE;                // 4096
  sbf_kernel<<<blocks, 256, 0, stream>>>(r, k, out);
}